// Round 4
// baseline (31.133 us; speedup 1.0000x reference)
//
#include <hip/hip_runtime.h>

#define GS 1000
#define NCP 16

typedef float f32x4 __attribute__((ext_vector_type(4)));
typedef float f32x2 __attribute__((ext_vector_type(2)));

// ---------- kernel 1: tiny pair-table build --------------------------------
// ws2[i] = (g[i], g[min(i+1,GS-1)]),  g[i] = dot(basis_grid[i], control_points)
__device__ __forceinline__ float dot16(const float* __restrict__ row,
                                       f32x4 c0, f32x4 c1, f32x4 c2, f32x4 c3) {
    const f32x4* r4 = reinterpret_cast<const f32x4*>(row);
    f32x4 a0 = r4[0], a1 = r4[1], a2 = r4[2], a3 = r4[3];
    float s = a0.x * c0.x;
    s = fmaf(a0.y, c0.y, s); s = fmaf(a0.z, c0.z, s); s = fmaf(a0.w, c0.w, s);
    s = fmaf(a1.x, c1.x, s); s = fmaf(a1.y, c1.y, s); s = fmaf(a1.z, c1.z, s); s = fmaf(a1.w, c1.w, s);
    s = fmaf(a2.x, c2.x, s); s = fmaf(a2.y, c2.y, s); s = fmaf(a2.z, c2.z, s); s = fmaf(a2.w, c2.w, s);
    s = fmaf(a3.x, c3.x, s); s = fmaf(a3.y, c3.y, s); s = fmaf(a3.z, c3.z, s); s = fmaf(a3.w, c3.w, s);
    return s;
}

__global__ __launch_bounds__(256) void build_table_kernel(
    const float* __restrict__ cp,
    const float* __restrict__ bg,
    f32x2* __restrict__ ws2)
{
    int i = blockIdx.x * 256 + threadIdx.x;
    if (i >= GS) return;
    const f32x4* c4 = reinterpret_cast<const f32x4*>(cp);
    f32x4 c0 = c4[0], c1 = c4[1], c2 = c4[2], c3 = c4[3];
    int i1 = min(i + 1, GS - 1);
    float g0 = dot16(bg + i * NCP, c0, c1, c2, c3);
    float g1 = dot16(bg + i1 * NCP, c0, c1, c2, c3);
    f32x2 p; p.x = g0; p.y = g1;
    ws2[i] = p;
}

// ---------- kernel 2: streaming lerp ---------------------------------------
__device__ __forceinline__ float evalone(float v, const f32x2* __restrict__ tbl) {
    // ind = clamp((v - (-3)) * (999/6), 0, 999); 166.5 and endpoints exact in fp32
    float ind = fmaf(v, 166.5f, 499.5f);
    ind = fminf(fmaxf(ind, 0.0f), 999.0f);
    float fl = truncf(ind);            // == floor, ind >= 0
    float w  = ind - fl;
    f32x2 p = tbl[(int)fl];            // one ds_read_b64; pair encodes min(f+1,999)
    return fmaf(w, p.y - p.x, p.x);
}

__device__ __forceinline__ f32x4 eval4(f32x4 v, const f32x2* __restrict__ tbl) {
    f32x4 r;
    r.x = evalone(v.x, tbl);
    r.y = evalone(v.y, tbl);
    r.z = evalone(v.z, tbl);
    r.w = evalone(v.w, tbl);
    return r;
}

__global__ __launch_bounds__(256) void bspline_main_kernel(
    const float* __restrict__ x,
    const f32x2* __restrict__ ws2,
    float* __restrict__ out,
    int n4)
{
    __shared__ f32x2 tbl[GS];
    const int tid = threadIdx.x;
    const int stride = gridDim.x * 256;
    const f32x4* __restrict__ x4 = reinterpret_cast<const f32x4*>(x);
    f32x4* __restrict__ o4 = reinterpret_cast<f32x4*>(out);

    int i = blockIdx.x * 256 + tid;

    // Peel batch-0 loads ABOVE the table staging: HBM latency hides the prologue.
    bool full = (i + 3 * stride < n4);
    f32x4 a, b, c, d;
    if (full) {
        a = x4[i];
        b = x4[i + stride];
        c = x4[i + 2 * stride];
        d = x4[i + 3 * stride];
    }

    // Stage the 8 KB pair table (500 float4-sized chunks) from ws.
    {
        const f32x4* __restrict__ src = reinterpret_cast<const f32x4*>(ws2);
        f32x4* dst = reinterpret_cast<f32x4*>(tbl);
        dst[tid] = src[tid];
        if (tid < GS / 2 - 256) dst[256 + tid] = src[256 + tid];
    }
    __syncthreads();

    while (full) {
        f32x4 ra = eval4(a, tbl);
        f32x4 rb = eval4(b, tbl);
        f32x4 rc = eval4(c, tbl);
        f32x4 rd = eval4(d, tbl);
        int ni = i + 4 * stride;
        bool nfull = (ni + 3 * stride < n4);
        if (nfull) {                   // prefetch next batch BEFORE the stores
            a = x4[ni];
            b = x4[ni + stride];
            c = x4[ni + 2 * stride];
            d = x4[ni + 3 * stride];
        }
        __builtin_nontemporal_store(ra, &o4[i]);
        __builtin_nontemporal_store(rb, &o4[i + stride]);
        __builtin_nontemporal_store(rc, &o4[i + 2 * stride]);
        __builtin_nontemporal_store(rd, &o4[i + 3 * stride]);
        i = ni;
        full = nfull;
    }
    for (; i < n4; i += stride) {      // tail (not taken when n4 % (4*stride) == 0)
        f32x4 v = x4[i];
        __builtin_nontemporal_store(eval4(v, tbl), &o4[i]);
    }
}

// ---------- fallback: single-kernel (no ws) --------------------------------
__global__ __launch_bounds__(256) void bspline_lut_kernel(
    const float* __restrict__ x,
    const float* __restrict__ cp,
    const float* __restrict__ bg,
    float* __restrict__ out,
    int n4)
{
    __shared__ float tbl[GS];
    for (int i = threadIdx.x; i < GS; i += 256) {
        const float* row = bg + i * NCP;
        float s = 0.0f;
        #pragma unroll
        for (int j = 0; j < NCP; ++j) s += row[j] * cp[j];
        tbl[i] = s;
    }
    __syncthreads();
    int idx = blockIdx.x * blockDim.x + threadIdx.x;
    int stride = gridDim.x * blockDim.x;
    for (int i = idx; i < n4; i += stride) {
        f32x4 v = reinterpret_cast<const f32x4*>(x)[i];
        f32x4 r;
        #pragma unroll
        for (int j = 0; j < 4; ++j) {
            float ind = fmaf(v[j], 166.5f, 499.5f);
            ind = fminf(fmaxf(ind, 0.0f), 999.0f);
            float fl = truncf(ind);
            float w  = ind - fl;
            int f = (int)fl;
            int cc = min(f + 1, GS - 1);
            r[j] = fmaf(w, tbl[cc] - tbl[f], tbl[f]);
        }
        reinterpret_cast<f32x4*>(out)[i] = r;
    }
}

extern "C" void kernel_launch(void* const* d_in, const int* in_sizes, int n_in,
                              void* d_out, int out_size, void* d_ws, size_t ws_size,
                              hipStream_t stream) {
    const float* x  = (const float*)d_in[0];
    const float* cp = (const float*)d_in[1];
    const float* bg = (const float*)d_in[2];
    float* out = (float*)d_out;

    int n = in_sizes[0];              // 16777216, divisible by 4
    int n4 = n / 4;

    int blocks = (n4 + 255) / 256;
    if (blocks > 2048) blocks = 2048; // 8 blocks/CU = 32 waves/CU (max occupancy)

    if (ws_size >= GS * sizeof(f32x2)) {
        f32x2* ws2 = (f32x2*)d_ws;
        build_table_kernel<<<(GS + 255) / 256, 256, 0, stream>>>(cp, bg, ws2);
        bspline_main_kernel<<<blocks, 256, 0, stream>>>(x, ws2, out, n4);
    } else {
        bspline_lut_kernel<<<blocks, 256, 0, stream>>>(x, cp, bg, out, n4);
    }
}

// Round 5
// 30.512 us; speedup vs baseline: 1.0204x; 1.0204x over previous
//
#include <hip/hip_runtime.h>

#define GS 1000
#define NCP 16

typedef float f32x4 __attribute__((ext_vector_type(4)));
typedef float f32x2 __attribute__((ext_vector_type(2)));

// ---------- kernel 1: tiny pair-table build --------------------------------
// ws2[i] = (g[i], g[min(i+1,GS-1)]),  g[i] = dot(basis_grid[i], control_points)
__device__ __forceinline__ float dot16(const float* __restrict__ row,
                                       f32x4 c0, f32x4 c1, f32x4 c2, f32x4 c3) {
    const f32x4* r4 = reinterpret_cast<const f32x4*>(row);
    f32x4 a0 = r4[0], a1 = r4[1], a2 = r4[2], a3 = r4[3];
    float s = a0.x * c0.x;
    s = fmaf(a0.y, c0.y, s); s = fmaf(a0.z, c0.z, s); s = fmaf(a0.w, c0.w, s);
    s = fmaf(a1.x, c1.x, s); s = fmaf(a1.y, c1.y, s); s = fmaf(a1.z, c1.z, s); s = fmaf(a1.w, c1.w, s);
    s = fmaf(a2.x, c2.x, s); s = fmaf(a2.y, c2.y, s); s = fmaf(a2.z, c2.z, s); s = fmaf(a2.w, c2.w, s);
    s = fmaf(a3.x, c3.x, s); s = fmaf(a3.y, c3.y, s); s = fmaf(a3.z, c3.z, s); s = fmaf(a3.w, c3.w, s);
    return s;
}

__global__ __launch_bounds__(256) void build_table_kernel(
    const float* __restrict__ cp,
    const float* __restrict__ bg,
    f32x2* __restrict__ ws2)
{
    int i = blockIdx.x * 256 + threadIdx.x;
    if (i >= GS) return;
    const f32x4* c4 = reinterpret_cast<const f32x4*>(cp);
    f32x4 c0 = c4[0], c1 = c4[1], c2 = c4[2], c3 = c4[3];
    int i1 = min(i + 1, GS - 1);
    float g0 = dot16(bg + i * NCP, c0, c1, c2, c3);
    float g1 = dot16(bg + i1 * NCP, c0, c1, c2, c3);
    f32x2 p; p.x = g0; p.y = g1;
    ws2[i] = p;
}

// ---------- kernel 2: streaming lerp, contiguous per-block chunks ----------
__device__ __forceinline__ float evalone(float v, const f32x2* __restrict__ tbl) {
    // ind = clamp((v + 3) * (999/6), 0, 999); 166.5 and endpoints exact in fp32
    float ind = fmaf(v, 166.5f, 499.5f);
    ind = fminf(fmaxf(ind, 0.0f), 999.0f);
    float fl = truncf(ind);            // == floor, ind >= 0
    float w  = ind - fl;
    f32x2 p = tbl[(int)fl];            // one ds_read_b64; pair encodes min(f+1,999)
    return fmaf(w, p.y - p.x, p.x);
}

__device__ __forceinline__ f32x4 eval4(f32x4 v, const f32x2* __restrict__ tbl) {
    f32x4 r;
    r.x = evalone(v.x, tbl);
    r.y = evalone(v.y, tbl);
    r.z = evalone(v.z, tbl);
    r.w = evalone(v.w, tbl);
    return r;
}

__global__ __launch_bounds__(256) void bspline_main_kernel(
    const float* __restrict__ x,
    const f32x2* __restrict__ ws2,
    float* __restrict__ out,
    int n4, int per_block)
{
    __shared__ f32x2 tbl[GS];
    const int tid = threadIdx.x;
    const f32x4* __restrict__ x4 = reinterpret_cast<const f32x4*>(x);
    f32x4* __restrict__ o4 = reinterpret_cast<f32x4*>(out);

    const int base = blockIdx.x * per_block;            // float4 units
    const int end  = min(base + per_block, n4);

    int i = base + tid;
    // Thread's batch: i, i+256, i+512, i+768 — block reads a contiguous 16 KB span.
    bool full = (i + 768 < end);
    f32x4 a, b, c, d;
    if (full) {                                          // peel above staging
        a = __builtin_nontemporal_load(&x4[i]);
        b = __builtin_nontemporal_load(&x4[i + 256]);
        c = __builtin_nontemporal_load(&x4[i + 512]);
        d = __builtin_nontemporal_load(&x4[i + 768]);
    }

    // Stage the 8 KB pair table (500 f32x4) from ws — hidden under the loads.
    {
        const f32x4* __restrict__ src = reinterpret_cast<const f32x4*>(ws2);
        f32x4* dst = reinterpret_cast<f32x4*>(tbl);
        dst[tid] = src[tid];
        if (tid < GS / 2 - 256) dst[256 + tid] = src[256 + tid];
    }
    __syncthreads();

    while (full) {
        f32x4 ra = eval4(a, tbl);
        f32x4 rb = eval4(b, tbl);
        f32x4 rc = eval4(c, tbl);
        f32x4 rd = eval4(d, tbl);
        int ni = i + 1024;
        bool nfull = (ni + 768 < end);
        if (nfull) {                                     // prefetch before stores
            a = __builtin_nontemporal_load(&x4[ni]);
            b = __builtin_nontemporal_load(&x4[ni + 256]);
            c = __builtin_nontemporal_load(&x4[ni + 512]);
            d = __builtin_nontemporal_load(&x4[ni + 768]);
        }
        __builtin_nontemporal_store(ra, &o4[i]);
        __builtin_nontemporal_store(rb, &o4[i + 256]);
        __builtin_nontemporal_store(rc, &o4[i + 512]);
        __builtin_nontemporal_store(rd, &o4[i + 768]);
        i = ni;
        full = nfull;
    }
    for (; i < end; i += 256) {                          // ragged tail (unused when exact)
        f32x4 v = __builtin_nontemporal_load(&x4[i]);
        __builtin_nontemporal_store(eval4(v, tbl), &o4[i]);
    }
}

// ---------- fallback: single-kernel (no ws) --------------------------------
__global__ __launch_bounds__(256) void bspline_lut_kernel(
    const float* __restrict__ x,
    const float* __restrict__ cp,
    const float* __restrict__ bg,
    float* __restrict__ out,
    int n4)
{
    __shared__ float tbl[GS];
    for (int i = threadIdx.x; i < GS; i += 256) {
        const float* row = bg + i * NCP;
        float s = 0.0f;
        #pragma unroll
        for (int j = 0; j < NCP; ++j) s += row[j] * cp[j];
        tbl[i] = s;
    }
    __syncthreads();
    int idx = blockIdx.x * blockDim.x + threadIdx.x;
    int stride = gridDim.x * blockDim.x;
    for (int i = idx; i < n4; i += stride) {
        f32x4 v = reinterpret_cast<const f32x4*>(x)[i];
        f32x4 r;
        #pragma unroll
        for (int j = 0; j < 4; ++j) {
            float ind = fmaf(v[j], 166.5f, 499.5f);
            ind = fminf(fmaxf(ind, 0.0f), 999.0f);
            float fl = truncf(ind);
            float w  = ind - fl;
            int f = (int)fl;
            int cc = min(f + 1, GS - 1);
            r[j] = fmaf(w, tbl[cc] - tbl[f], tbl[f]);
        }
        reinterpret_cast<f32x4*>(out)[i] = r;
    }
}

extern "C" void kernel_launch(void* const* d_in, const int* in_sizes, int n_in,
                              void* d_out, int out_size, void* d_ws, size_t ws_size,
                              hipStream_t stream) {
    const float* x  = (const float*)d_in[0];
    const float* cp = (const float*)d_in[1];
    const float* bg = (const float*)d_in[2];
    float* out = (float*)d_out;

    int n = in_sizes[0];              // 16777216
    int n4 = n / 4;                   // 4194304 = 2048 * 2048 (exact)

    int blocks = 2048;                // 8 blocks/CU
    int per_block = (n4 + blocks - 1) / blocks;   // 2048 float4s = 32 KB per block

    if (ws_size >= GS * sizeof(f32x2)) {
        f32x2* ws2 = (f32x2*)d_ws;
        build_table_kernel<<<(GS + 255) / 256, 256, 0, stream>>>(cp, bg, ws2);
        bspline_main_kernel<<<blocks, 256, 0, stream>>>(x, ws2, out, n4, per_block);
    } else {
        bspline_lut_kernel<<<(n4 + 255) / 256 > 2048 ? 2048 : (n4 + 255) / 256,
                            256, 0, stream>>>(x, cp, bg, out, n4);
    }
}